// Round 6
// baseline (138.358 us; speedup 1.0000x reference)
//
#include <hip/hip_runtime.h>

#define NN 2048
#define DD 64
#define C1 0.36067376f  // 2/sqrt(D) * log2(e)
#define C1H 0.18033688f // C1/2

typedef _Float16 h8 __attribute__((ext_vector_type(8)));
typedef _Float16 h4 __attribute__((ext_vector_type(4)));
typedef float f32x16 __attribute__((ext_vector_type(16)));

union H8U4 { h8 v; unsigned u[4]; };

// ---- prep v2: fully-coalesced global access, LDS-mediated frag swizzle ----
// Ks[bh][jj][c][lane]{8}      = K[32jj+ln][16c+8lh+0..7]       (A-frag order)
// Vs[bh][jj][o][c][lane]{8}   = V[32jj+16c+8lh+jx][32o+ln]     (V^T A-frag order)
// hk[bh][n] = C1H*||k_n||^2
__global__ __launch_bounds__(256) void prep(const float* __restrict__ k,
                                            const float* __restrict__ v,
                                            _Float16* __restrict__ Ks,
                                            _Float16* __restrict__ Vs,
                                            float* __restrict__ hk) {
    __shared__ _Float16 T[128][72];    // 18.4 KB, reused for K then V
    const int tb = blockIdx.x, bh = blockIdx.y, tid = threadIdx.x;
    const size_t ibase = (size_t)bh * NN * DD + (size_t)tb * 128 * DD;
    const int lane = tid & 63, ln = lane & 31, lh = lane >> 5;

    // ---- K phase: coalesced load + f16 LDS + row sumsq ----
#pragma unroll
    for (int it = 0; it < 8; ++it) {
        int f = tid + 256 * it;        // 2048 float4 = 128 rows x 16
        int row = f >> 4, c4 = (f & 15) * 4;
        float4 a = *(const float4*)&k[ibase + (size_t)row * DD + c4];
        h4 hv = {(_Float16)a.x, (_Float16)a.y, (_Float16)a.z, (_Float16)a.w};
        *(h4*)&T[row][c4] = hv;
        float s = a.x * a.x + a.y * a.y + a.z * a.z + a.w * a.w;
        s += __shfl_xor(s, 1, 16);
        s += __shfl_xor(s, 2, 16);
        s += __shfl_xor(s, 4, 16);
        s += __shfl_xor(s, 8, 16);
        if ((tid & 15) == 0) hk[bh * NN + tb * 128 + row] = s * C1H;
    }
    __syncthreads();
    // frag gather from LDS, coalesced global store
#pragma unroll
    for (int it = 0; it < 4; ++it) {
        int f2 = tid + 256 * it;       // 1024 h8 = 16 combos x 64 lanes
        int combo = f2 >> 6;           // (jl, c)
        int jl = combo >> 2, c = combo & 3;
        h8 r = *(const h8*)&T[32 * jl + ln][16 * c + 8 * lh];
        *(h8*)&Ks[(size_t)bh * 131072 + (size_t)(4 * tb + jl) * 2048
                  + (size_t)(c * 64 + lane) * 8] = r;
    }
    __syncthreads();

    // ---- V phase: coalesced load + f16 LDS + transposed frag gather ----
#pragma unroll
    for (int it = 0; it < 8; ++it) {
        int f = tid + 256 * it;
        int row = f >> 4, c4 = (f & 15) * 4;
        float4 a = *(const float4*)&v[ibase + (size_t)row * DD + c4];
        h4 hv = {(_Float16)a.x, (_Float16)a.y, (_Float16)a.z, (_Float16)a.w};
        *(h4*)&T[row][c4] = hv;
    }
    __syncthreads();
#pragma unroll
    for (int it = 0; it < 4; ++it) {
        int f2 = tid + 256 * it;       // 1024 h8 = 16 combos x 64 lanes
        int combo = f2 >> 6;           // (jl, o, c)
        int jl = combo >> 2, o = (combo >> 1) & 1, c = combo & 1;
        h8 r;
#pragma unroll
        for (int jx = 0; jx < 8; ++jx)
            r[jx] = T[32 * jl + 16 * c + 8 * lh + jx][32 * o + ln];
        *(h8*)&Vs[(size_t)bh * 131072 + (size_t)(4 * tb + jl) * 2048
                  + (size_t)(o * 128 + c * 64 + lane) * 8] = r;
    }
}

// ---- main: barrier-free flash RBF; sched_barrier-pinned register pipeline ----
__global__ __launch_bounds__(128, 2) void rbf_attn(
    const float* __restrict__ q, const _Float16* __restrict__ Ks,
    const _Float16* __restrict__ Vs, const float* __restrict__ hk,
    float* __restrict__ out)
{
    const int tid = threadIdx.x;
    const int bh = blockIdx.x;
    const int qb = 31 - blockIdx.y;      // LPT: heaviest blocks dispatch first
    const int wv = tid >> 6, lane = tid & 63;
    const int ln = lane & 31, lh = lane >> 5;
    const int jmax = 2 * qb + wv;        // this wave's diagonal 32-key tile
    const int qrow = qb * 64 + wv * 32 + ln;
    const size_t fbase = (size_t)bh * NN * DD;

    // Q B-frags straight from global f32 (per-lane 16B-contiguous, L2-hot)
    h8 qf[4];
    {
        const float* qr = q + fbase + (size_t)qrow * DD;
#pragma unroll
        for (int c = 0; c < 4; ++c) {
            float4 a = *(const float4*)&qr[16 * c + 8 * lh];
            float4 b = *(const float4*)&qr[16 * c + 8 * lh + 4];
            qf[c] = h8{(_Float16)a.x, (_Float16)a.y, (_Float16)a.z, (_Float16)a.w,
                       (_Float16)b.x, (_Float16)b.y, (_Float16)b.z, (_Float16)b.w};
        }
    }

    const _Float16* Ksb = Ks + (size_t)bh * 131072;
    const _Float16* Vsb = Vs + (size_t)bh * 131072;
    const float4* hk4 = (const float4*)(hk + bh * NN);
    const int klq = (lh * 32 + ln) * 8;  // element offset of this lane's frag

    f32x16 O0, O1;
#pragma unroll
    for (int r = 0; r < 16; ++r) { O0[r] = 0.f; O1[r] = 0.f; }
    float lsum = 0.f, mrun = -INFINITY;

    auto loadT = [&](int jj, h8 (&kf)[4], h8 (&vf)[4], float4 (&hr)[4]) {
        const _Float16* kp = Ksb + (size_t)jj * 2048 + klq;
        const _Float16* vp = Vsb + (size_t)jj * 2048 + klq;
#pragma unroll
        for (int c = 0; c < 4; ++c) kf[c] = *(const h8*)(kp + c * 512);
#pragma unroll
        for (int oc = 0; oc < 4; ++oc)
            vf[oc] = *(const h8*)(vp + (oc >> 1) * 1024 + (oc & 1) * 512);
#pragma unroll
        for (int g = 0; g < 4; ++g) hr[g] = hk4[jj * 8 + g * 2 + lh];
    };

    auto comp = [&](int jj, h8 (&kf)[4], h8 (&vf)[4], float4 (&hr)[4]) {
        f32x16 S;
#pragma unroll
        for (int r = 0; r < 16; ++r) S[r] = 0.f;
#pragma unroll
        for (int c = 0; c < 4; ++c)
            S = __builtin_amdgcn_mfma_f32_32x32x16_f16(kf[c], qf[c], S, 0, 0, 0);

        const bool diag = (jj == jmax);
        float x[16];
#pragma unroll
        for (int r = 0; r < 16; ++r) {
            const float* hf = (const float*)&hr[r >> 2];
            float xv = fmaf(S[r], C1, -hf[r & 3]);
            if (diag) {
                int keyloc = (r & 3) + 8 * (r >> 2) + 4 * lh;
                if (keyloc > ln) xv = -INFINITY;
            }
            x[r] = xv;
        }
        float mt = x[0];
#pragma unroll
        for (int r = 1; r < 16; ++r) mt = fmaxf(mt, x[r]);
        mt = fmaxf(mt, __shfl_xor(mt, 32));
        // ballot-gated rescale: max rarely rises after early tiles
        if (__ballot(mt > mrun) != 0ull) {
            float mnew = fmaxf(mrun, mt);
            float alpha = __builtin_amdgcn_exp2f(mrun - mnew);
            mrun = mnew;
            lsum *= alpha;
#pragma unroll
            for (int r = 0; r < 16; ++r) { O0[r] *= alpha; O1[r] *= alpha; }
        }
        float p[16], ps = 0.f;
#pragma unroll
        for (int r = 0; r < 16; ++r) {
            p[r] = __builtin_amdgcn_exp2f(x[r] - mrun);
            ps += p[r];
        }
        lsum += ps;

        unsigned pk[8];
#pragma unroll
        for (int hh = 0; hh < 8; ++hh) {
            auto pr = __builtin_amdgcn_cvt_pkrtz(p[2 * hh], p[2 * hh + 1]);
            unsigned pu; __builtin_memcpy(&pu, &pr, 4);
            pk[hh] = pu;
        }
#pragma unroll
        for (int s = 0; s < 2; ++s) {       // C-frag -> B-frag(P^T): lane^32 swap
            unsigned send0 = lh ? pk[4 * s + 0] : pk[4 * s + 2];
            unsigned send1 = lh ? pk[4 * s + 1] : pk[4 * s + 3];
            unsigned r0 = (unsigned)__shfl_xor((int)send0, 32);
            unsigned r1 = (unsigned)__shfl_xor((int)send1, 32);
            H8U4 pb;
            pb.u[0] = lh ? r0 : pk[4 * s + 0];
            pb.u[1] = lh ? r1 : pk[4 * s + 1];
            pb.u[2] = lh ? pk[4 * s + 2] : r0;
            pb.u[3] = lh ? pk[4 * s + 3] : r1;
            O0 = __builtin_amdgcn_mfma_f32_32x32x16_f16(vf[s], pb.v, O0, 0, 0, 0);
            O1 = __builtin_amdgcn_mfma_f32_32x32x16_f16(vf[2 + s], pb.v, O1, 0, 0, 0);
        }
    };

    // rotated 2-deep register pipeline; sched_barrier(0) pins prefetch issue
    h8 kfA[4], vfA[4]; float4 hrA[4];
    h8 kfB[4], vfB[4]; float4 hrB[4];
    loadT(0, kfA, vfA, hrA);
    __builtin_amdgcn_sched_barrier(0);
    int jj = 0;
    while (true) {
        if (jj < jmax) loadT(jj + 1, kfB, vfB, hrB);
        __builtin_amdgcn_sched_barrier(0);
        comp(jj, kfA, vfA, hrA);
        __builtin_amdgcn_sched_barrier(0);
        if (++jj > jmax) break;
        if (jj < jmax) loadT(jj + 1, kfA, vfA, hrA);
        __builtin_amdgcn_sched_barrier(0);
        comp(jj, kfB, vfB, hrB);
        __builtin_amdgcn_sched_barrier(0);
        if (++jj > jmax) break;
    }

    // epilogue: l = own + partner(lane^32); normalized float4 stores
    float lt = lsum + __shfl_xor(lsum, 32);
    float inv = 1.f / lt;
    size_t ro = fbase + (size_t)qrow * DD;
#pragma unroll
    for (int g = 0; g < 4; ++g) {
        float4 o0 = make_float4(O0[4 * g + 0] * inv, O0[4 * g + 1] * inv,
                                O0[4 * g + 2] * inv, O0[4 * g + 3] * inv);
        *(float4*)&out[ro + 8 * g + 4 * lh] = o0;
        float4 o1 = make_float4(O1[4 * g + 0] * inv, O1[4 * g + 1] * inv,
                                O1[4 * g + 2] * inv, O1[4 * g + 3] * inv);
        *(float4*)&out[ro + 32 + 8 * g + 4 * lh] = o1;
    }
}

extern "C" void kernel_launch(void* const* d_in, const int* in_sizes, int n_in,
                              void* d_out, int out_size, void* d_ws, size_t ws_size,
                              hipStream_t stream) {
    (void)in_sizes; (void)n_in; (void)out_size; (void)ws_size;
    const float* q = (const float*)d_in[0];
    const float* k = (const float*)d_in[1];
    const float* v = (const float*)d_in[2];
    float* out = (float*)d_out;

    // ws: [hk 256KB][Ks 8MB f16][Vs 8MB f16]
    float* hk = (float*)d_ws;
    _Float16* Ks = (_Float16*)((char*)d_ws + 262144);
    _Float16* Vs = (_Float16*)((char*)d_ws + 262144 + 8388608);

    prep<<<dim3(16, 32), 256, 0, stream>>>(k, v, Ks, Vs, hk);
    rbf_attn<<<dim3(32, 32), 128, 0, stream>>>(q, Ks, Vs, hk, out);
}